// Round 5
// baseline (11017.326 us; speedup 1.0000x reference)
//
#include <hip/hip_runtime.h>

// PointNet++ SetAbstraction: FPS -> ball query -> grouped MLP(67->64->64->128, BN+ReLU) -> maxpool
// B=8, N=8192, S=2048, K=32, F=64.
//
// d_in order: 0 xyzs, 1 feats, then per layer i=1..3: w,b,g,bt,m,v.
// d_out: [8][2048][3] center_xyzs followed by [8][2048][128] center_feats (fp32).
// d_ws: 16576 floats (66.3 KB) of transposed weights.
//
// EXACTNESS INVARIANTS (validated R4: absmax 7.8e-3 < 5.4e-2):
//   - discrete-decision math in contract(off) helpers; __f*_rn does NOT block FMA.
//   - np.sum last-axis n=3: FORWARD plain adds (x0+x1)+x2  [FPS dist, |c|^2, |x|^2]
//   - einsum dot: ascending FMA chain fma(c2,x2, fma(c1,x1, c0*x0))  [ball query]
//   - FPS argmax / scan: first-index tie-break (total order -> any reduce shape OK).
//
// R5 change: FPS kernel restructured (512 thr, 16 pts/thread, coords carried
// through the reduction in registers -> zero memory ops on the serial path).
// sa_fused_kernel byte-identical to the R4 passing version.

#define NPTS 8192
#define SCTR 2048
#define NB   8
#define KNN  32
#define NF   64

// d = (dx*dx + dy*dy) + dz*dz, exact fp32 mul/add order, NO contraction.
__device__ __forceinline__ float fps_sqdist(float ax, float ay, float az,
                                            float bx, float by, float bz) {
#pragma clang fp contract(off)
  float dx = ax - bx;
  float dy = ay - by;
  float dz = az - bz;
  return (dx * dx + dy * dy) + dz * dz;
}

// (x*x + y*y) + z*z, NO contraction (np.sum forward order, n=3).
__device__ __forceinline__ float sumsq3(float x, float y, float z) {
#pragma clang fp contract(off)
  return (x * x + y * y) + z * z;
}

// Ball-query expanded form: (sc + sx) - 2*dot, NO contraction on the adds.
// dot = ascending-k FMA chain: fma(cz,z, fma(cy,y, cx*x)).
__device__ __forceinline__ float bq_d2(float sc, float sx,
                                       float cx, float cy, float cz,
                                       float x, float y, float z) {
#pragma clang fp contract(off)
  float dt = fmaf(cz, z, fmaf(cy, y, cx * x));
  return (sc + sx) - 2.0f * dt;
}

// ---------------------------------------------------------------------------
// Kernel 1: blocks 0..7 = FPS (one block per batch, 512 thr = 8 waves,
// 16 points/thread); blocks 8..40 = weight transpose into workspace.
// Serial path per step is register/LDS only: winner coords ride the reduce.
// ---------------------------------------------------------------------------
__global__ __launch_bounds__(512) void fps_transpose_kernel(
    const float* __restrict__ xyzs,
    const float* __restrict__ w1, const float* __restrict__ w2, const float* __restrict__ w3,
    float* __restrict__ centers, float* __restrict__ wT)
{
  const int t = threadIdx.x;
  if (blockIdx.x >= NB) {
    int idx = (blockIdx.x - NB) * 512 + t;
    if (idx < 67*64) {
      int c = idx >> 6, o = idx & 63;
      wT[idx] = w1[o*67 + c];
    } else if (idx < 67*64 + 64*64) {
      int r = idx - 67*64; int c = r >> 6, o = r & 63;
      wT[idx] = w2[o*64 + c];
    } else if (idx < 67*64 + 64*64 + 64*128) {
      int r = idx - (67*64 + 64*64); int c = r >> 7, o = r & 127;
      wT[idx] = w3[o*64 + c];
    }
    return;
  }

  const int b = blockIdx.x;
  const float* xb = xyzs + (size_t)b * NPTS * 3;

  // 16 points per thread, p = t*16 + j (ascending global index within thread).
  float px[16], py[16], pz[16], mind[16];
  {
    const float4* s4 = (const float4*)xb + t * 12;  // 12 float4 = 48 floats = 16 pts
#pragma unroll
    for (int q = 0; q < 4; ++q) {
      float4 v0 = s4[3*q+0], v1 = s4[3*q+1], v2 = s4[3*q+2];
      int j = 4*q;
      px[j+0]=v0.x; py[j+0]=v0.y; pz[j+0]=v0.z;
      px[j+1]=v0.w; py[j+1]=v1.x; pz[j+1]=v1.y;
      px[j+2]=v1.z; py[j+2]=v1.w; pz[j+2]=v2.x;
      px[j+3]=v2.y; py[j+3]=v2.z; pz[j+3]=v2.w;
    }
#pragma unroll
    for (int j = 0; j < 16; ++j) mind[j] = 1e10f;  // same f32 as ref's 1e10
  }

  __shared__ float redv[2][8], redx[2][8], redy[2][8], redz[2][8];
  __shared__ int   redi[2][8];
  __shared__ int   hist[SCTR];
  if (t == 0) hist[0] = 0;  // reference: first center is index 0

  // Center 0 coords: one-time broadcast global load (off the steady-state path).
  float lx = xb[0], ly = xb[1], lz = xb[2];

  for (int s = 1; s < SCTR; ++s) {
    float bv = -1.0f; int bj = 0;
#pragma unroll
    for (int j = 0; j < 16; ++j) {
      float d = fps_sqdist(px[j], py[j], pz[j], lx, ly, lz);
      float m = fminf(mind[j], d);
      mind[j] = m;
      if (m > bv) { bv = m; bj = j; }   // strict > keeps smallest j (first-index argmax)
    }
    int gi = t * 16 + bj;

    // Select local-best coords from registers: 4-level binary tree on bj bits
    // (constant indices only -> stays in VGPRs, pure bit-exact moves).
    float wx, wy, wz;
    {
      float tx[8], ty[8], tz[8];
      bool s0 = (bj & 1);
#pragma unroll
      for (int i = 0; i < 8; ++i) {
        tx[i] = s0 ? px[2*i+1] : px[2*i];
        ty[i] = s0 ? py[2*i+1] : py[2*i];
        tz[i] = s0 ? pz[2*i+1] : pz[2*i];
      }
      bool s1 = (bj & 2);
#pragma unroll
      for (int i = 0; i < 4; ++i) {
        tx[i] = s1 ? tx[2*i+1] : tx[2*i];
        ty[i] = s1 ? ty[2*i+1] : ty[2*i];
        tz[i] = s1 ? tz[2*i+1] : tz[2*i];
      }
      bool s2 = (bj & 4);
#pragma unroll
      for (int i = 0; i < 2; ++i) {
        tx[i] = s2 ? tx[2*i+1] : tx[2*i];
        ty[i] = s2 ? ty[2*i+1] : ty[2*i];
        tz[i] = s2 ? tz[2*i+1] : tz[2*i];
      }
      bool s3 = (bj & 8);
      wx = s3 ? tx[1] : tx[0];
      wy = s3 ? ty[1] : ty[0];
      wz = s3 ? tz[1] : tz[0];
    }

    // Wave-level argmax butterfly carrying (bv, gi, wx, wy, wz);
    // first-index tie-break keeps np.argmax semantics under any reduce shape.
#pragma unroll
    for (int mm = 1; mm < 64; mm <<= 1) {
      float ov = __shfl_xor(bv, mm);
      int   oi = __shfl_xor(gi, mm);
      float ox = __shfl_xor(wx, mm);
      float oy = __shfl_xor(wy, mm);
      float oz = __shfl_xor(wz, mm);
      if (ov > bv || (ov == bv && oi < gi)) { bv = ov; gi = oi; wx = ox; wy = oy; wz = oz; }
    }

    int pb = s & 1;  // double-buffered cross-wave scratch: one barrier per step
    if ((t & 63) == 0) {
      int w = t >> 6;
      redv[pb][w] = bv; redi[pb][w] = gi;
      redx[pb][w] = wx; redy[pb][w] = wy; redz[pb][w] = wz;
    }
    __syncthreads();

    // Cross-wave scan: value+index compare chain over 8 entries, then one
    // dynamic-index broadcast LDS read of the winning wave's coords.
    float v0 = redv[pb][0]; int i0 = redi[pb][0]; int w0 = 0;
#pragma unroll
    for (int w = 1; w < 8; ++w) {
      float v1 = redv[pb][w]; int i1 = redi[pb][w];
      if (v1 > v0 || (v1 == v0 && i1 < i0)) { v0 = v1; i0 = i1; w0 = w; }
    }
    lx = redx[pb][w0]; ly = redy[pb][w0]; lz = redz[pb][w0];
    if (t == 0) hist[s] = i0;
  }
  __syncthreads();

  for (int s = t; s < SCTR; s += 512) {
    int i = hist[s];
    float* o = centers + ((size_t)b * SCTR + s) * 3;
    o[0] = xb[i*3+0]; o[1] = xb[i*3+1]; o[2] = xb[i*3+2];
  }
}

// ---------------------------------------------------------------------------
// Kernel 2: one 64-thread wave per center. Ball query (first K ascending
// index within radius, exact expanded-form d2), gather to LDS, 3-layer MLP
// with per-lane 4k x 8o register tile, BN+ReLU, maxpool over K, store.
// (byte-identical to the R4 passing version)
// ---------------------------------------------------------------------------
__global__ __launch_bounds__(64) void sa_fused_kernel(
    const float* __restrict__ xyzs, const float* __restrict__ feats,
    const float* centers, const float* __restrict__ wT,
    const float* __restrict__ b1, const float* __restrict__ g1, const float* __restrict__ bt1,
    const float* __restrict__ m1, const float* __restrict__ v1,
    const float* __restrict__ b2, const float* __restrict__ g2, const float* __restrict__ bt2,
    const float* __restrict__ m2, const float* __restrict__ v2,
    const float* __restrict__ b3, const float* __restrict__ g3, const float* __restrict__ bt3,
    const float* __restrict__ m3, const float* __restrict__ v3,
    float* out_feats)
{
  constexpr float R2 = (float)(0.2 * 0.2);  // f32(0.04000000000000001) — matches ref predicate
  const int bid  = blockIdx.x;
  const int b    = bid >> 11;
  const int lane = threadIdx.x;
  const float* xb = xyzs + (size_t)b * NPTS * 3;
  const float* cp = centers + (size_t)bid * 3;
  float cx = cp[0], cy = cp[1], cz = cp[2];
  float sc = sumsq3(cx, cy, cz);

  __shared__ int   gidx[KNN];
  __shared__ float in_[32*67];   // stride 67 (conflict-free for the 4k in-reads)
  __shared__ float y_[32*65];    // stride 65

  // ---- ball query: first 32 in-radius points by ascending index ----
  int cnt = 0;
  for (int base = 0; base < NPTS && cnt < KNN; base += 64) {
    int n = base + lane;
    float x = xb[n*3+0], y = xb[n*3+1], z = xb[n*3+2];
    float sx = sumsq3(x, y, z);
    float d2 = bq_d2(sc, sx, cx, cy, cz, x, y, z);
    bool within = (d2 <= R2);
    unsigned long long mk = __ballot(within);
    int rank = __popcll(mk & ((1ull << lane) - 1ull));
    int slot = cnt + rank;
    if (within && slot < KNN) gidx[slot] = n;
    cnt += (int)__popcll(mk);
  }
  if (cnt > KNN) cnt = KNN;
  __syncthreads();

  // ---- gather: in_[k][0..2] = xyz - center, in_[k][3..66] = feats; zeros if invalid ----
#pragma unroll 4
  for (int k = 0; k < KNN; ++k) {
    int gk = (k < cnt) ? gidx[k] : -1;
    float fv = 0.f, xv = 0.f;
    if (gk >= 0) {
      fv = feats[((size_t)b * NPTS + gk) * NF + lane];
      if (lane < 3) xv = xb[gk*3 + lane] - cp[lane];  // exact single op
    }
    in_[k*67 + 3 + lane] = fv;
    if (lane < 3) in_[k*67 + lane] = xv;
  }
  __syncthreads();

  const int g = lane >> 3;  // k-group: k = 4g..4g+3
  const int h = lane & 7;   // o-group: o = 8h..8h+7
  const float* w1T = wT;                  // [67][64]
  const float* w2T = wT + 67*64;          // [64][64]
  const float* w3T = wT + 67*64 + 64*64;  // [64][128]

  // ---- Layer 1: 67 -> 64 ----
  {
    float acc[4][8];
#pragma unroll
    for (int i=0;i<4;++i)
#pragma unroll
      for (int j=0;j<8;++j) acc[i][j]=0.f;
    for (int c = 0; c < 67; ++c) {
      float a0 = in_[(4*g+0)*67 + c];
      float a1 = in_[(4*g+1)*67 + c];
      float a2 = in_[(4*g+2)*67 + c];
      float a3 = in_[(4*g+3)*67 + c];
      const float* wr = w1T + c*64 + 8*h;
      float4 wv0 = *(const float4*)(wr);
      float4 wv1 = *(const float4*)(wr + 4);
      float wj[8] = {wv0.x,wv0.y,wv0.z,wv0.w,wv1.x,wv1.y,wv1.z,wv1.w};
#pragma unroll
      for (int j=0;j<8;++j) {
        acc[0][j] = fmaf(a0, wj[j], acc[0][j]);
        acc[1][j] = fmaf(a1, wj[j], acc[1][j]);
        acc[2][j] = fmaf(a2, wj[j], acc[2][j]);
        acc[3][j] = fmaf(a3, wj[j], acc[3][j]);
      }
    }
    float scl[8], shf[8];
#pragma unroll
    for (int j=0;j<8;++j) {
      int o = 8*h + j;
      float r = g1[o] * rsqrtf(v1[o] + 1e-5f);
      scl[j] = r;
      shf[j] = (b1[o] - m1[o]) * r + bt1[o];
    }
#pragma unroll
    for (int i=0;i<4;++i) {
      int k = 4*g + i;
#pragma unroll
      for (int j=0;j<8;++j)
        y_[k*65 + 8*h + j] = fmaxf(fmaf(acc[i][j], scl[j], shf[j]), 0.f);
    }
  }
  __syncthreads();

  // ---- Layer 2: 64 -> 64 (reads y_, writes in_ reused at stride 65) ----
  {
    float acc[4][8];
#pragma unroll
    for (int i=0;i<4;++i)
#pragma unroll
      for (int j=0;j<8;++j) acc[i][j]=0.f;
    for (int c = 0; c < 64; ++c) {
      float a0 = y_[(4*g+0)*65 + c];
      float a1 = y_[(4*g+1)*65 + c];
      float a2 = y_[(4*g+2)*65 + c];
      float a3 = y_[(4*g+3)*65 + c];
      const float* wr = w2T + c*64 + 8*h;
      float4 wv0 = *(const float4*)(wr);
      float4 wv1 = *(const float4*)(wr + 4);
      float wj[8] = {wv0.x,wv0.y,wv0.z,wv0.w,wv1.x,wv1.y,wv1.z,wv1.w};
#pragma unroll
      for (int j=0;j<8;++j) {
        acc[0][j] = fmaf(a0, wj[j], acc[0][j]);
        acc[1][j] = fmaf(a1, wj[j], acc[1][j]);
        acc[2][j] = fmaf(a2, wj[j], acc[2][j]);
        acc[3][j] = fmaf(a3, wj[j], acc[3][j]);
      }
    }
    float scl[8], shf[8];
#pragma unroll
    for (int j=0;j<8;++j) {
      int o = 8*h + j;
      float r = g2[o] * rsqrtf(v2[o] + 1e-5f);
      scl[j] = r;
      shf[j] = (b2[o] - m2[o]) * r + bt2[o];
    }
    __syncthreads();  // order old in_ reads before overwrite
#pragma unroll
    for (int i=0;i<4;++i) {
      int k = 4*g + i;
#pragma unroll
      for (int j=0;j<8;++j)
        in_[k*65 + 8*h + j] = fmaxf(fmaf(acc[i][j], scl[j], shf[j]), 0.f);
    }
  }
  __syncthreads();

  // ---- Layer 3: 64 -> 128 in two o-passes, BN+ReLU, maxpool over k, store ----
  for (int p = 0; p < 2; ++p) {
    float acc[4][8];
#pragma unroll
    for (int i=0;i<4;++i)
#pragma unroll
      for (int j=0;j<8;++j) acc[i][j]=0.f;
    for (int c = 0; c < 64; ++c) {
      float a0 = in_[(4*g+0)*65 + c];
      float a1 = in_[(4*g+1)*65 + c];
      float a2 = in_[(4*g+2)*65 + c];
      float a3 = in_[(4*g+3)*65 + c];
      const float* wr = w3T + c*128 + p*64 + 8*h;
      float4 wv0 = *(const float4*)(wr);
      float4 wv1 = *(const float4*)(wr + 4);
      float wj[8] = {wv0.x,wv0.y,wv0.z,wv0.w,wv1.x,wv1.y,wv1.z,wv1.w};
#pragma unroll
      for (int j=0;j<8;++j) {
        acc[0][j] = fmaf(a0, wj[j], acc[0][j]);
        acc[1][j] = fmaf(a1, wj[j], acc[1][j]);
        acc[2][j] = fmaf(a2, wj[j], acc[2][j]);
        acc[3][j] = fmaf(a3, wj[j], acc[3][j]);
      }
    }
    float scl[8], shf[8];
#pragma unroll
    for (int j=0;j<8;++j) {
      int o = p*64 + 8*h + j;
      float r = g3[o] * rsqrtf(v3[o] + 1e-5f);
      scl[j] = r;
      shf[j] = (b3[o] - m3[o]) * r + bt3[o];
    }
    float vm[8];
#pragma unroll
    for (int j=0;j<8;++j) {
      float q0 = fmaxf(fmaf(acc[0][j], scl[j], shf[j]), 0.f);
      float q1 = fmaxf(fmaf(acc[1][j], scl[j], shf[j]), 0.f);
      float q2 = fmaxf(fmaf(acc[2][j], scl[j], shf[j]), 0.f);
      float q3 = fmaxf(fmaf(acc[3][j], scl[j], shf[j]), 0.f);
      vm[j] = fmaxf(fmaxf(q0,q1), fmaxf(q2,q3));
    }
#pragma unroll
    for (int mk = 8; mk < 64; mk <<= 1) {
#pragma unroll
      for (int j=0;j<8;++j) vm[j] = fmaxf(vm[j], __shfl_xor(vm[j], mk));
    }
    if (g == 0) {
      float* dst = out_feats + (size_t)bid*128 + p*64 + 8*h;
      *(float4*)dst       = make_float4(vm[0],vm[1],vm[2],vm[3]);
      *(float4*)(dst + 4) = make_float4(vm[4],vm[5],vm[6],vm[7]);
    }
  }
}

// ---------------------------------------------------------------------------
extern "C" void kernel_launch(void* const* d_in, const int* in_sizes, int n_in,
                              void* d_out, int out_size, void* d_ws, size_t ws_size,
                              hipStream_t stream) {
  const float* xyzs  = (const float*)d_in[0];
  const float* feats = (const float*)d_in[1];
  const float* w1  = (const float*)d_in[2];
  const float* b1  = (const float*)d_in[3];
  const float* g1  = (const float*)d_in[4];
  const float* bt1 = (const float*)d_in[5];
  const float* m1  = (const float*)d_in[6];
  const float* v1  = (const float*)d_in[7];
  const float* w2  = (const float*)d_in[8];
  const float* b2  = (const float*)d_in[9];
  const float* g2  = (const float*)d_in[10];
  const float* bt2 = (const float*)d_in[11];
  const float* m2  = (const float*)d_in[12];
  const float* v2  = (const float*)d_in[13];
  const float* w3  = (const float*)d_in[14];
  const float* b3  = (const float*)d_in[15];
  const float* g3  = (const float*)d_in[16];
  const float* bt3 = (const float*)d_in[17];
  const float* m3  = (const float*)d_in[18];
  const float* v3  = (const float*)d_in[19];

  float* out       = (float*)d_out;
  float* centers   = out;                          // [8][2048][3]
  float* out_feats = out + (size_t)NB * SCTR * 3;  // [8][2048][128]
  float* wT        = (float*)d_ws;                 // 16576 floats

  // blocks 0..7: FPS; blocks 8..40: weight transpose (33 blocks x 512 thr)
  hipLaunchKernelGGL(fps_transpose_kernel, dim3(NB + 33), dim3(512), 0, stream,
                     xyzs, w1, w2, w3, centers, wT);
  hipLaunchKernelGGL(sa_fused_kernel, dim3(NB * SCTR), dim3(64), 0, stream,
                     xyzs, feats, centers, wT,
                     b1, g1, bt1, m1, v1,
                     b2, g2, bt2, m2, v2,
                     b3, g3, bt3, m3, v3,
                     out_feats);
}

// Round 6
// 4221.876 us; speedup vs baseline: 2.6096x; 2.6096x over previous
//
#include <hip/hip_runtime.h>

// PointNet++ SetAbstraction: FPS -> ball query -> grouped MLP(67->64->64->128, BN+ReLU) -> maxpool
// B=8, N=8192, S=2048, K=32, F=64.
//
// d_out: [8][2048][3] center_xyzs then [8][2048][128] center_feats (fp32).
// d_ws: 16576 floats of transposed weights.
//
// EXACTNESS INVARIANTS (validated R4: absmax 7.8e-3 < 5.4e-2):
//   - discrete-decision math in contract(off) helpers; __f*_rn does NOT block FMA.
//   - np.sum last-axis n=3: FORWARD plain adds (x0+x1)+x2  [FPS dist, |c|^2, |x|^2]
//   - einsum dot: ascending FMA chain fma(c2,x2, fma(c1,x1, c0*x0))  [ball query]
//   - FPS argmax / scan: first-index tie-break (total order -> any reduce shape OK).
//
// R6 LESSON (from R4/R5 counters): per-thread float arrays here get demoted to
// LDS (AMDGPUPromoteAlloca -> 1.1e7 bank conflicts) and/or spilled to scratch
// (GB-scale FETCH/WRITE). FPS is rebuilt spill-proof: points live in LDS planar
// arrays (wave-contiguous ds_read_b128), per-thread state is 4 named float4s.
// sa_fused_kernel byte-identical to the R4 passing version.

#define NPTS 8192
#define SCTR 2048
#define NB   8
#define KNN  32
#define NF   64

// d = (dx*dx + dy*dy) + dz*dz, exact fp32 mul/add order, NO contraction.
__device__ __forceinline__ float fps_sqdist(float ax, float ay, float az,
                                            float bx, float by, float bz) {
#pragma clang fp contract(off)
  float dx = ax - bx;
  float dy = ay - by;
  float dz = az - bz;
  return (dx * dx + dy * dy) + dz * dz;
}

// (x*x + y*y) + z*z, NO contraction (np.sum forward order, n=3).
__device__ __forceinline__ float sumsq3(float x, float y, float z) {
#pragma clang fp contract(off)
  return (x * x + y * y) + z * z;
}

// Ball-query expanded form: (sc + sx) - 2*dot, NO contraction on the adds.
// dot = ascending-k FMA chain: fma(cz,z, fma(cy,y, cx*x)).
__device__ __forceinline__ float bq_d2(float sc, float sx,
                                       float cx, float cy, float cz,
                                       float x, float y, float z) {
#pragma clang fp contract(off)
  float dt = fmaf(cz, z, fmaf(cy, y, cx * x));
  return (sc + sx) - 2.0f * dt;
}

// ---------------------------------------------------------------------------
// Kernel 1: blocks 0..7 = FPS (one block per batch, 512 thr = 8 waves,
// 16 points/thread as 4 quads strided 2048); blocks 8..40 = weight transpose.
// Points in LDS planes; per-thread state = 4 named float4 mind vectors.
// Quad q of thread t covers global indices q*2048 + 4t .. +3, so each wave's
// ds_read_b128 is lane-contiguous (lane L -> offset L*16 B): conflict-free.
// ---------------------------------------------------------------------------
__global__ __launch_bounds__(512, 2) void fps_transpose_kernel(
    const float* __restrict__ xyzs,
    const float* __restrict__ w1, const float* __restrict__ w2, const float* __restrict__ w3,
    float* __restrict__ centers, float* __restrict__ wT)
{
  const int t = threadIdx.x;
  if (blockIdx.x >= NB) {
    int idx = (blockIdx.x - NB) * 512 + t;
    if (idx < 67*64) {
      int c = idx >> 6, o = idx & 63;
      wT[idx] = w1[o*67 + c];
    } else if (idx < 67*64 + 64*64) {
      int r = idx - 67*64; int c = r >> 6, o = r & 63;
      wT[idx] = w2[o*64 + c];
    } else if (idx < 67*64 + 64*64 + 64*128) {
      int r = idx - (67*64 + 64*64); int c = r >> 7, o = r & 127;
      wT[idx] = w3[o*64 + c];
    }
    return;
  }

  const int b = blockIdx.x;
  const float* xb = xyzs + (size_t)b * NPTS * 3;

  __shared__ float sX[NPTS], sY[NPTS], sZ[NPTS];   // 96 KB planar coords
  __shared__ float redv[2][8];
  __shared__ int   redi[2][8];
  __shared__ int   hist[SCTR];                      // 8 KB

  // One-time fill of the planar LDS copies (coalesced-ish, off the hot path).
  for (int i = t; i < NPTS; i += 512) {
    sX[i] = xb[3*i+0];
    sY[i] = xb[3*i+1];
    sZ[i] = xb[3*i+2];
  }
  if (t == 0) hist[0] = 0;   // reference: first center is index 0
  __syncthreads();

  // Per-thread min-distance state: 4 named float4s (16 pts) — nothing indexable.
  float4 mA = make_float4(1e10f,1e10f,1e10f,1e10f);
  float4 mB = mA, mC = mA, mD = mA;

  float lx = sX[0], ly = sY[0], lz = sZ[0];

#define FPS_QUAD(MV, QOFF)                                                        \
  do {                                                                            \
    const float4 qx = *(const float4*)(sX + (QOFF) + 4*t);                        \
    const float4 qy = *(const float4*)(sY + (QOFF) + 4*t);                        \
    const float4 qz = *(const float4*)(sZ + (QOFF) + 4*t);                        \
    float d, m;                                                                   \
    d = fps_sqdist(qx.x, qy.x, qz.x, lx, ly, lz);                                 \
    m = fminf(MV.x, d); MV.x = m; if (m > bv) { bv = m; bg = (QOFF) + 4*t + 0; }  \
    d = fps_sqdist(qx.y, qy.y, qz.y, lx, ly, lz);                                 \
    m = fminf(MV.y, d); MV.y = m; if (m > bv) { bv = m; bg = (QOFF) + 4*t + 1; }  \
    d = fps_sqdist(qx.z, qy.z, qz.z, lx, ly, lz);                                 \
    m = fminf(MV.z, d); MV.z = m; if (m > bv) { bv = m; bg = (QOFF) + 4*t + 2; }  \
    d = fps_sqdist(qx.w, qy.w, qz.w, lx, ly, lz);                                 \
    m = fminf(MV.w, d); MV.w = m; if (m > bv) { bv = m; bg = (QOFF) + 4*t + 3; }  \
  } while (0)

  for (int s = 1; s < SCTR; ++s) {
    float bv = -1.0f; int bg = 0;
    FPS_QUAD(mA, 0);
    FPS_QUAD(mB, 2048);
    FPS_QUAD(mC, 4096);
    FPS_QUAD(mD, 6144);

    // Wave-level argmax butterfly on (bv, bg); first-index tie-break preserves
    // np.argmax semantics under any reduction shape (strict total order).
#pragma unroll
    for (int mm = 1; mm < 64; mm <<= 1) {
      float ov = __shfl_xor(bv, mm);
      int   og = __shfl_xor(bg, mm);
      if (ov > bv || (ov == bv && og < bg)) { bv = ov; bg = og; }
    }

    int pb = s & 1;   // double-buffered cross-wave scratch: one barrier per step
    if ((t & 63) == 0) { int w = t >> 6; redv[pb][w] = bv; redi[pb][w] = bg; }
    __syncthreads();

    float v0 = redv[pb][0]; int i0 = redi[pb][0];
#pragma unroll
    for (int w = 1; w < 8; ++w) {
      float v1 = redv[pb][w]; int i1 = redi[pb][w];
      if (v1 > v0 || (v1 == v0 && i1 < i0)) { v0 = v1; i0 = i1; }
    }
    // Winner coords: broadcast LDS reads (same address all lanes — free).
    lx = sX[i0]; ly = sY[i0]; lz = sZ[i0];
    if (t == 0) hist[s] = i0;
  }
#undef FPS_QUAD
  __syncthreads();

  for (int s = t; s < SCTR; s += 512) {
    int i = hist[s];
    float* o = centers + ((size_t)b * SCTR + s) * 3;
    o[0] = sX[i]; o[1] = sY[i]; o[2] = sZ[i];
  }
}

// ---------------------------------------------------------------------------
// Kernel 2: one 64-thread wave per center. Ball query (first K ascending
// index within radius, exact expanded-form d2), gather to LDS, 3-layer MLP
// with per-lane 4k x 8o register tile, BN+ReLU, maxpool over K, store.
// (byte-identical to the R4 passing version)
// ---------------------------------------------------------------------------
__global__ __launch_bounds__(64) void sa_fused_kernel(
    const float* __restrict__ xyzs, const float* __restrict__ feats,
    const float* centers, const float* __restrict__ wT,
    const float* __restrict__ b1, const float* __restrict__ g1, const float* __restrict__ bt1,
    const float* __restrict__ m1, const float* __restrict__ v1,
    const float* __restrict__ b2, const float* __restrict__ g2, const float* __restrict__ bt2,
    const float* __restrict__ m2, const float* __restrict__ v2,
    const float* __restrict__ b3, const float* __restrict__ g3, const float* __restrict__ bt3,
    const float* __restrict__ m3, const float* __restrict__ v3,
    float* out_feats)
{
  constexpr float R2 = (float)(0.2 * 0.2);  // f32(0.04000000000000001) — matches ref predicate
  const int bid  = blockIdx.x;
  const int b    = bid >> 11;
  const int lane = threadIdx.x;
  const float* xb = xyzs + (size_t)b * NPTS * 3;
  const float* cp = centers + (size_t)bid * 3;
  float cx = cp[0], cy = cp[1], cz = cp[2];
  float sc = sumsq3(cx, cy, cz);

  __shared__ int   gidx[KNN];
  __shared__ float in_[32*67];   // stride 67 (conflict-free for the 4k in-reads)
  __shared__ float y_[32*65];    // stride 65

  // ---- ball query: first 32 in-radius points by ascending index ----
  int cnt = 0;
  for (int base = 0; base < NPTS && cnt < KNN; base += 64) {
    int n = base + lane;
    float x = xb[n*3+0], y = xb[n*3+1], z = xb[n*3+2];
    float sx = sumsq3(x, y, z);
    float d2 = bq_d2(sc, sx, cx, cy, cz, x, y, z);
    bool within = (d2 <= R2);
    unsigned long long mk = __ballot(within);
    int rank = __popcll(mk & ((1ull << lane) - 1ull));
    int slot = cnt + rank;
    if (within && slot < KNN) gidx[slot] = n;
    cnt += (int)__popcll(mk);
  }
  if (cnt > KNN) cnt = KNN;
  __syncthreads();

  // ---- gather: in_[k][0..2] = xyz - center, in_[k][3..66] = feats; zeros if invalid ----
#pragma unroll 4
  for (int k = 0; k < KNN; ++k) {
    int gk = (k < cnt) ? gidx[k] : -1;
    float fv = 0.f, xv = 0.f;
    if (gk >= 0) {
      fv = feats[((size_t)b * NPTS + gk) * NF + lane];
      if (lane < 3) xv = xb[gk*3 + lane] - cp[lane];  // exact single op
    }
    in_[k*67 + 3 + lane] = fv;
    if (lane < 3) in_[k*67 + lane] = xv;
  }
  __syncthreads();

  const int g = lane >> 3;  // k-group: k = 4g..4g+3
  const int h = lane & 7;   // o-group: o = 8h..8h+7
  const float* w1T = wT;                  // [67][64]
  const float* w2T = wT + 67*64;          // [64][64]
  const float* w3T = wT + 67*64 + 64*64;  // [64][128]

  // ---- Layer 1: 67 -> 64 ----
  {
    float acc[4][8];
#pragma unroll
    for (int i=0;i<4;++i)
#pragma unroll
      for (int j=0;j<8;++j) acc[i][j]=0.f;
    for (int c = 0; c < 67; ++c) {
      float a0 = in_[(4*g+0)*67 + c];
      float a1 = in_[(4*g+1)*67 + c];
      float a2 = in_[(4*g+2)*67 + c];
      float a3 = in_[(4*g+3)*67 + c];
      const float* wr = w1T + c*64 + 8*h;
      float4 wv0 = *(const float4*)(wr);
      float4 wv1 = *(const float4*)(wr + 4);
      float wj[8] = {wv0.x,wv0.y,wv0.z,wv0.w,wv1.x,wv1.y,wv1.z,wv1.w};
#pragma unroll
      for (int j=0;j<8;++j) {
        acc[0][j] = fmaf(a0, wj[j], acc[0][j]);
        acc[1][j] = fmaf(a1, wj[j], acc[1][j]);
        acc[2][j] = fmaf(a2, wj[j], acc[2][j]);
        acc[3][j] = fmaf(a3, wj[j], acc[3][j]);
      }
    }
    float scl[8], shf[8];
#pragma unroll
    for (int j=0;j<8;++j) {
      int o = 8*h + j;
      float r = g1[o] * rsqrtf(v1[o] + 1e-5f);
      scl[j] = r;
      shf[j] = (b1[o] - m1[o]) * r + bt1[o];
    }
#pragma unroll
    for (int i=0;i<4;++i) {
      int k = 4*g + i;
#pragma unroll
      for (int j=0;j<8;++j)
        y_[k*65 + 8*h + j] = fmaxf(fmaf(acc[i][j], scl[j], shf[j]), 0.f);
    }
  }
  __syncthreads();

  // ---- Layer 2: 64 -> 64 (reads y_, writes in_ reused at stride 65) ----
  {
    float acc[4][8];
#pragma unroll
    for (int i=0;i<4;++i)
#pragma unroll
      for (int j=0;j<8;++j) acc[i][j]=0.f;
    for (int c = 0; c < 64; ++c) {
      float a0 = y_[(4*g+0)*65 + c];
      float a1 = y_[(4*g+1)*65 + c];
      float a2 = y_[(4*g+2)*65 + c];
      float a3 = y_[(4*g+3)*65 + c];
      const float* wr = w2T + c*64 + 8*h;
      float4 wv0 = *(const float4*)(wr);
      float4 wv1 = *(const float4*)(wr + 4);
      float wj[8] = {wv0.x,wv0.y,wv0.z,wv0.w,wv1.x,wv1.y,wv1.z,wv1.w};
#pragma unroll
      for (int j=0;j<8;++j) {
        acc[0][j] = fmaf(a0, wj[j], acc[0][j]);
        acc[1][j] = fmaf(a1, wj[j], acc[1][j]);
        acc[2][j] = fmaf(a2, wj[j], acc[2][j]);
        acc[3][j] = fmaf(a3, wj[j], acc[3][j]);
      }
    }
    float scl[8], shf[8];
#pragma unroll
    for (int j=0;j<8;++j) {
      int o = 8*h + j;
      float r = g2[o] * rsqrtf(v2[o] + 1e-5f);
      scl[j] = r;
      shf[j] = (b2[o] - m2[o]) * r + bt2[o];
    }
    __syncthreads();  // order old in_ reads before overwrite
#pragma unroll
    for (int i=0;i<4;++i) {
      int k = 4*g + i;
#pragma unroll
      for (int j=0;j<8;++j)
        in_[k*65 + 8*h + j] = fmaxf(fmaf(acc[i][j], scl[j], shf[j]), 0.f);
    }
  }
  __syncthreads();

  // ---- Layer 3: 64 -> 128 in two o-passes, BN+ReLU, maxpool over k, store ----
  for (int p = 0; p < 2; ++p) {
    float acc[4][8];
#pragma unroll
    for (int i=0;i<4;++i)
#pragma unroll
      for (int j=0;j<8;++j) acc[i][j]=0.f;
    for (int c = 0; c < 64; ++c) {
      float a0 = in_[(4*g+0)*65 + c];
      float a1 = in_[(4*g+1)*65 + c];
      float a2 = in_[(4*g+2)*65 + c];
      float a3 = in_[(4*g+3)*65 + c];
      const float* wr = w3T + c*128 + p*64 + 8*h;
      float4 wv0 = *(const float4*)(wr);
      float4 wv1 = *(const float4*)(wr + 4);
      float wj[8] = {wv0.x,wv0.y,wv0.z,wv0.w,wv1.x,wv1.y,wv1.z,wv1.w};
#pragma unroll
      for (int j=0;j<8;++j) {
        acc[0][j] = fmaf(a0, wj[j], acc[0][j]);
        acc[1][j] = fmaf(a1, wj[j], acc[1][j]);
        acc[2][j] = fmaf(a2, wj[j], acc[2][j]);
        acc[3][j] = fmaf(a3, wj[j], acc[3][j]);
      }
    }
    float scl[8], shf[8];
#pragma unroll
    for (int j=0;j<8;++j) {
      int o = p*64 + 8*h + j;
      float r = g3[o] * rsqrtf(v3[o] + 1e-5f);
      scl[j] = r;
      shf[j] = (b3[o] - m3[o]) * r + bt3[o];
    }
    float vm[8];
#pragma unroll
    for (int j=0;j<8;++j) {
      float q0 = fmaxf(fmaf(acc[0][j], scl[j], shf[j]), 0.f);
      float q1 = fmaxf(fmaf(acc[1][j], scl[j], shf[j]), 0.f);
      float q2 = fmaxf(fmaf(acc[2][j], scl[j], shf[j]), 0.f);
      float q3 = fmaxf(fmaf(acc[3][j], scl[j], shf[j]), 0.f);
      vm[j] = fmaxf(fmaxf(q0,q1), fmaxf(q2,q3));
    }
#pragma unroll
    for (int mk = 8; mk < 64; mk <<= 1) {
#pragma unroll
      for (int j=0;j<8;++j) vm[j] = fmaxf(vm[j], __shfl_xor(vm[j], mk));
    }
    if (g == 0) {
      float* dst = out_feats + (size_t)bid*128 + p*64 + 8*h;
      *(float4*)dst       = make_float4(vm[0],vm[1],vm[2],vm[3]);
      *(float4*)(dst + 4) = make_float4(vm[4],vm[5],vm[6],vm[7]);
    }
  }
}

// ---------------------------------------------------------------------------
extern "C" void kernel_launch(void* const* d_in, const int* in_sizes, int n_in,
                              void* d_out, int out_size, void* d_ws, size_t ws_size,
                              hipStream_t stream) {
  const float* xyzs  = (const float*)d_in[0];
  const float* feats = (const float*)d_in[1];
  const float* w1  = (const float*)d_in[2];
  const float* b1  = (const float*)d_in[3];
  const float* g1  = (const float*)d_in[4];
  const float* bt1 = (const float*)d_in[5];
  const float* m1  = (const float*)d_in[6];
  const float* v1  = (const float*)d_in[7];
  const float* w2  = (const float*)d_in[8];
  const float* b2  = (const float*)d_in[9];
  const float* g2  = (const float*)d_in[10];
  const float* bt2 = (const float*)d_in[11];
  const float* m2  = (const float*)d_in[12];
  const float* v2  = (const float*)d_in[13];
  const float* w3  = (const float*)d_in[14];
  const float* b3  = (const float*)d_in[15];
  const float* g3  = (const float*)d_in[16];
  const float* bt3 = (const float*)d_in[17];
  const float* m3  = (const float*)d_in[18];
  const float* v3  = (const float*)d_in[19];

  float* out       = (float*)d_out;
  float* centers   = out;                          // [8][2048][3]
  float* out_feats = out + (size_t)NB * SCTR * 3;  // [8][2048][128]
  float* wT        = (float*)d_ws;                 // 16576 floats

  // blocks 0..7: FPS; blocks 8..40: weight transpose (33 blocks x 512 thr)
  hipLaunchKernelGGL(fps_transpose_kernel, dim3(NB + 33), dim3(512), 0, stream,
                     xyzs, w1, w2, w3, centers, wT);
  hipLaunchKernelGGL(sa_fused_kernel, dim3(NB * SCTR), dim3(64), 0, stream,
                     xyzs, feats, centers, wT,
                     b1, g1, bt1, m1, v1,
                     b2, g2, bt2, m2, v2,
                     b3, g3, bt3, m3, v3,
                     out_feats);
}

// Round 7
// 4024.483 us; speedup vs baseline: 2.7376x; 1.0490x over previous
//
#include <hip/hip_runtime.h>

// PointNet++ SetAbstraction: FPS -> ball query -> grouped MLP(67->64->64->128, BN+ReLU) -> maxpool
// B=8, N=8192, S=2048, K=32, F=64.
//
// d_out: [8][2048][3] center_xyzs then [8][2048][128] center_feats (fp32).
// d_ws: 16576 floats of transposed weights.
//
// EXACTNESS INVARIANTS (validated R4/R6: absmax 7.8e-3 < 5.4e-2):
//   - discrete-decision math in contract(off) helpers; __f*_rn does NOT block FMA.
//   - np.sum last-axis n=3: FORWARD plain adds (x0+x1)+x2  [FPS dist, |c|^2, |x|^2]
//   - einsum dot: ascending FMA chain fma(c2,x2, fma(c1,x1, c0*x0))  [ball query]
//   - FPS argmax / scan: first-index tie-break (total order -> any reduce shape OK).
//
// PERF LESSONS:
//   R5: dynamically-indexed per-thread arrays get LDS-demoted (1.1e7 bank
//       conflicts) — use named vectors in unrolled straight-line code only.
//   R6: FETCH/WRITE_SIZE are KB — no scratch spilling anywhere; FPS step cost
//       4330 cyc, ~1150 of it re-ds_read'ing loop-invariant coords + LDS-pipe
//       contention with the shuffle butterfly.
//   R7 change: coords hoisted to named float4 registers before the step loop;
//       zero per-step ds_reads. sa_fused_kernel byte-identical to R4.

#define NPTS 8192
#define SCTR 2048
#define NB   8
#define KNN  32
#define NF   64

// d = (dx*dx + dy*dy) + dz*dz, exact fp32 mul/add order, NO contraction.
__device__ __forceinline__ float fps_sqdist(float ax, float ay, float az,
                                            float bx, float by, float bz) {
#pragma clang fp contract(off)
  float dx = ax - bx;
  float dy = ay - by;
  float dz = az - bz;
  return (dx * dx + dy * dy) + dz * dz;
}

// (x*x + y*y) + z*z, NO contraction (np.sum forward order, n=3).
__device__ __forceinline__ float sumsq3(float x, float y, float z) {
#pragma clang fp contract(off)
  return (x * x + y * y) + z * z;
}

// Ball-query expanded form: (sc + sx) - 2*dot, NO contraction on the adds.
// dot = ascending-k FMA chain: fma(cz,z, fma(cy,y, cx*x)).
__device__ __forceinline__ float bq_d2(float sc, float sx,
                                       float cx, float cy, float cz,
                                       float x, float y, float z) {
#pragma clang fp contract(off)
  float dt = fmaf(cz, z, fmaf(cy, y, cx * x));
  return (sc + sx) - 2.0f * dt;
}

// ---------------------------------------------------------------------------
// Kernel 1: blocks 0..7 = FPS (one block per batch, 512 thr = 8 waves,
// 16 points/thread held in NAMED float4 registers across the whole loop);
// blocks 8..40 = weight transpose. LDS planes kept only for the winner-coord
// broadcast lookup and the final writeback.
// ---------------------------------------------------------------------------
__global__ __launch_bounds__(512, 2) void fps_transpose_kernel(
    const float* __restrict__ xyzs,
    const float* __restrict__ w1, const float* __restrict__ w2, const float* __restrict__ w3,
    float* __restrict__ centers, float* __restrict__ wT)
{
  const int t = threadIdx.x;
  if (blockIdx.x >= NB) {
    int idx = (blockIdx.x - NB) * 512 + t;
    if (idx < 67*64) {
      int c = idx >> 6, o = idx & 63;
      wT[idx] = w1[o*67 + c];
    } else if (idx < 67*64 + 64*64) {
      int r = idx - 67*64; int c = r >> 6, o = r & 63;
      wT[idx] = w2[o*64 + c];
    } else if (idx < 67*64 + 64*64 + 64*128) {
      int r = idx - (67*64 + 64*64); int c = r >> 7, o = r & 127;
      wT[idx] = w3[o*64 + c];
    }
    return;
  }

  const int b = blockIdx.x;
  const float* xb = xyzs + (size_t)b * NPTS * 3;

  __shared__ float sX[NPTS], sY[NPTS], sZ[NPTS];   // 96 KB planar coords
  __shared__ float redv[2][8];
  __shared__ int   redi[2][8];
  __shared__ int   hist[SCTR];                      // 8 KB

  // One-time fill of the planar LDS copies (off the hot path).
  for (int i = t; i < NPTS; i += 512) {
    sX[i] = xb[3*i+0];
    sY[i] = xb[3*i+1];
    sZ[i] = xb[3*i+2];
  }
  if (t == 0) hist[0] = 0;   // reference: first center is index 0
  __syncthreads();

  const int t4 = 4 * t;

  // Hoist all 16 points (4 quads strided 2048) into NAMED registers — loop
  // invariant, read once. Named float4s in straight-line code stay in VGPRs
  // (R6-verified pattern); never index these dynamically (R5 lesson).
  const float4 xA = *(const float4*)(sX + 0    + t4);
  const float4 yA = *(const float4*)(sY + 0    + t4);
  const float4 zA = *(const float4*)(sZ + 0    + t4);
  const float4 xB = *(const float4*)(sX + 2048 + t4);
  const float4 yB = *(const float4*)(sY + 2048 + t4);
  const float4 zB = *(const float4*)(sZ + 2048 + t4);
  const float4 xC = *(const float4*)(sX + 4096 + t4);
  const float4 yC = *(const float4*)(sY + 4096 + t4);
  const float4 zC = *(const float4*)(sZ + 4096 + t4);
  const float4 xD = *(const float4*)(sX + 6144 + t4);
  const float4 yD = *(const float4*)(sY + 6144 + t4);
  const float4 zD = *(const float4*)(sZ + 6144 + t4);

  // Per-thread min-distance state: 4 named float4s (16 pts).
  float4 mA = make_float4(1e10f,1e10f,1e10f,1e10f);
  float4 mB = mA, mC = mA, mD = mA;

  float lx = sX[0], ly = sY[0], lz = sZ[0];

#define FPS_PT(MX, MY, MZ, MM, IDX)                                         \
  do {                                                                      \
    float d = fps_sqdist(MX, MY, MZ, lx, ly, lz);                           \
    float m = fminf(MM, d); MM = m;                                         \
    if (m > bv) { bv = m; bg = (IDX); }                                     \
  } while (0)

#define FPS_QUAD(QX, QY, QZ, MV, QOFF)                                      \
  do {                                                                      \
    FPS_PT(QX.x, QY.x, QZ.x, MV.x, (QOFF) + t4 + 0);                        \
    FPS_PT(QX.y, QY.y, QZ.y, MV.y, (QOFF) + t4 + 1);                        \
    FPS_PT(QX.z, QY.z, QZ.z, MV.z, (QOFF) + t4 + 2);                        \
    FPS_PT(QX.w, QY.w, QZ.w, MV.w, (QOFF) + t4 + 3);                        \
  } while (0)

  for (int s = 1; s < SCTR; ++s) {
    float bv = -1.0f; int bg = 0;
    FPS_QUAD(xA, yA, zA, mA, 0);
    FPS_QUAD(xB, yB, zB, mB, 2048);
    FPS_QUAD(xC, yC, zC, mC, 4096);
    FPS_QUAD(xD, yD, zD, mD, 6144);

    // Wave-level argmax butterfly on (bv, bg); first-index tie-break preserves
    // np.argmax semantics under any reduction shape (strict total order).
#pragma unroll
    for (int mm = 1; mm < 64; mm <<= 1) {
      float ov = __shfl_xor(bv, mm);
      int   og = __shfl_xor(bg, mm);
      if (ov > bv || (ov == bv && og < bg)) { bv = ov; bg = og; }
    }

    int pb = s & 1;   // double-buffered cross-wave scratch: one barrier per step
    if ((t & 63) == 0) { int w = t >> 6; redv[pb][w] = bv; redi[pb][w] = bg; }
    __syncthreads();

    float v0 = redv[pb][0]; int i0 = redi[pb][0];
#pragma unroll
    for (int w = 1; w < 8; ++w) {
      float v1 = redv[pb][w]; int i1 = redi[pb][w];
      if (v1 > v0 || (v1 == v0 && i1 < i0)) { v0 = v1; i0 = i1; }
    }
    // Winner coords: broadcast LDS reads (same address all lanes — free).
    lx = sX[i0]; ly = sY[i0]; lz = sZ[i0];
    if (t == 0) hist[s] = i0;
  }
#undef FPS_QUAD
#undef FPS_PT
  __syncthreads();

  for (int s = t; s < SCTR; s += 512) {
    int i = hist[s];
    float* o = centers + ((size_t)b * SCTR + s) * 3;
    o[0] = sX[i]; o[1] = sY[i]; o[2] = sZ[i];
  }
}

// ---------------------------------------------------------------------------
// Kernel 2: one 64-thread wave per center. Ball query (first K ascending
// index within radius, exact expanded-form d2), gather to LDS, 3-layer MLP
// with per-lane 4k x 8o register tile, BN+ReLU, maxpool over K, store.
// (byte-identical to the R4 passing version)
// ---------------------------------------------------------------------------
__global__ __launch_bounds__(64) void sa_fused_kernel(
    const float* __restrict__ xyzs, const float* __restrict__ feats,
    const float* centers, const float* __restrict__ wT,
    const float* __restrict__ b1, const float* __restrict__ g1, const float* __restrict__ bt1,
    const float* __restrict__ m1, const float* __restrict__ v1,
    const float* __restrict__ b2, const float* __restrict__ g2, const float* __restrict__ bt2,
    const float* __restrict__ m2, const float* __restrict__ v2,
    const float* __restrict__ b3, const float* __restrict__ g3, const float* __restrict__ bt3,
    const float* __restrict__ m3, const float* __restrict__ v3,
    float* out_feats)
{
  constexpr float R2 = (float)(0.2 * 0.2);  // f32(0.04000000000000001) — matches ref predicate
  const int bid  = blockIdx.x;
  const int b    = bid >> 11;
  const int lane = threadIdx.x;
  const float* xb = xyzs + (size_t)b * NPTS * 3;
  const float* cp = centers + (size_t)bid * 3;
  float cx = cp[0], cy = cp[1], cz = cp[2];
  float sc = sumsq3(cx, cy, cz);

  __shared__ int   gidx[KNN];
  __shared__ float in_[32*67];   // stride 67 (conflict-free for the 4k in-reads)
  __shared__ float y_[32*65];    // stride 65

  // ---- ball query: first 32 in-radius points by ascending index ----
  int cnt = 0;
  for (int base = 0; base < NPTS && cnt < KNN; base += 64) {
    int n = base + lane;
    float x = xb[n*3+0], y = xb[n*3+1], z = xb[n*3+2];
    float sx = sumsq3(x, y, z);
    float d2 = bq_d2(sc, sx, cx, cy, cz, x, y, z);
    bool within = (d2 <= R2);
    unsigned long long mk = __ballot(within);
    int rank = __popcll(mk & ((1ull << lane) - 1ull));
    int slot = cnt + rank;
    if (within && slot < KNN) gidx[slot] = n;
    cnt += (int)__popcll(mk);
  }
  if (cnt > KNN) cnt = KNN;
  __syncthreads();

  // ---- gather: in_[k][0..2] = xyz - center, in_[k][3..66] = feats; zeros if invalid ----
#pragma unroll 4
  for (int k = 0; k < KNN; ++k) {
    int gk = (k < cnt) ? gidx[k] : -1;
    float fv = 0.f, xv = 0.f;
    if (gk >= 0) {
      fv = feats[((size_t)b * NPTS + gk) * NF + lane];
      if (lane < 3) xv = xb[gk*3 + lane] - cp[lane];  // exact single op
    }
    in_[k*67 + 3 + lane] = fv;
    if (lane < 3) in_[k*67 + lane] = xv;
  }
  __syncthreads();

  const int g = lane >> 3;  // k-group: k = 4g..4g+3
  const int h = lane & 7;   // o-group: o = 8h..8h+7
  const float* w1T = wT;                  // [67][64]
  const float* w2T = wT + 67*64;          // [64][64]
  const float* w3T = wT + 67*64 + 64*64;  // [64][128]

  // ---- Layer 1: 67 -> 64 ----
  {
    float acc[4][8];
#pragma unroll
    for (int i=0;i<4;++i)
#pragma unroll
      for (int j=0;j<8;++j) acc[i][j]=0.f;
    for (int c = 0; c < 67; ++c) {
      float a0 = in_[(4*g+0)*67 + c];
      float a1 = in_[(4*g+1)*67 + c];
      float a2 = in_[(4*g+2)*67 + c];
      float a3 = in_[(4*g+3)*67 + c];
      const float* wr = w1T + c*64 + 8*h;
      float4 wv0 = *(const float4*)(wr);
      float4 wv1 = *(const float4*)(wr + 4);
      float wj[8] = {wv0.x,wv0.y,wv0.z,wv0.w,wv1.x,wv1.y,wv1.z,wv1.w};
#pragma unroll
      for (int j=0;j<8;++j) {
        acc[0][j] = fmaf(a0, wj[j], acc[0][j]);
        acc[1][j] = fmaf(a1, wj[j], acc[1][j]);
        acc[2][j] = fmaf(a2, wj[j], acc[2][j]);
        acc[3][j] = fmaf(a3, wj[j], acc[3][j]);
      }
    }
    float scl[8], shf[8];
#pragma unroll
    for (int j=0;j<8;++j) {
      int o = 8*h + j;
      float r = g1[o] * rsqrtf(v1[o] + 1e-5f);
      scl[j] = r;
      shf[j] = (b1[o] - m1[o]) * r + bt1[o];
    }
#pragma unroll
    for (int i=0;i<4;++i) {
      int k = 4*g + i;
#pragma unroll
      for (int j=0;j<8;++j)
        y_[k*65 + 8*h + j] = fmaxf(fmaf(acc[i][j], scl[j], shf[j]), 0.f);
    }
  }
  __syncthreads();

  // ---- Layer 2: 64 -> 64 (reads y_, writes in_ reused at stride 65) ----
  {
    float acc[4][8];
#pragma unroll
    for (int i=0;i<4;++i)
#pragma unroll
      for (int j=0;j<8;++j) acc[i][j]=0.f;
    for (int c = 0; c < 64; ++c) {
      float a0 = y_[(4*g+0)*65 + c];
      float a1 = y_[(4*g+1)*65 + c];
      float a2 = y_[(4*g+2)*65 + c];
      float a3 = y_[(4*g+3)*65 + c];
      const float* wr = w2T + c*64 + 8*h;
      float4 wv0 = *(const float4*)(wr);
      float4 wv1 = *(const float4*)(wr + 4);
      float wj[8] = {wv0.x,wv0.y,wv0.z,wv0.w,wv1.x,wv1.y,wv1.z,wv1.w};
#pragma unroll
      for (int j=0;j<8;++j) {
        acc[0][j] = fmaf(a0, wj[j], acc[0][j]);
        acc[1][j] = fmaf(a1, wj[j], acc[1][j]);
        acc[2][j] = fmaf(a2, wj[j], acc[2][j]);
        acc[3][j] = fmaf(a3, wj[j], acc[3][j]);
      }
    }
    float scl[8], shf[8];
#pragma unroll
    for (int j=0;j<8;++j) {
      int o = 8*h + j;
      float r = g2[o] * rsqrtf(v2[o] + 1e-5f);
      scl[j] = r;
      shf[j] = (b2[o] - m2[o]) * r + bt2[o];
    }
    __syncthreads();  // order old in_ reads before overwrite
#pragma unroll
    for (int i=0;i<4;++i) {
      int k = 4*g + i;
#pragma unroll
      for (int j=0;j<8;++j)
        in_[k*65 + 8*h + j] = fmaxf(fmaf(acc[i][j], scl[j], shf[j]), 0.f);
    }
  }
  __syncthreads();

  // ---- Layer 3: 64 -> 128 in two o-passes, BN+ReLU, maxpool over k, store ----
  for (int p = 0; p < 2; ++p) {
    float acc[4][8];
#pragma unroll
    for (int i=0;i<4;++i)
#pragma unroll
      for (int j=0;j<8;++j) acc[i][j]=0.f;
    for (int c = 0; c < 64; ++c) {
      float a0 = in_[(4*g+0)*65 + c];
      float a1 = in_[(4*g+1)*65 + c];
      float a2 = in_[(4*g+2)*65 + c];
      float a3 = in_[(4*g+3)*65 + c];
      const float* wr = w3T + c*128 + p*64 + 8*h;
      float4 wv0 = *(const float4*)(wr);
      float4 wv1 = *(const float4*)(wr + 4);
      float wj[8] = {wv0.x,wv0.y,wv0.z,wv0.w,wv1.x,wv1.y,wv1.z,wv1.w};
#pragma unroll
      for (int j=0;j<8;++j) {
        acc[0][j] = fmaf(a0, wj[j], acc[0][j]);
        acc[1][j] = fmaf(a1, wj[j], acc[1][j]);
        acc[2][j] = fmaf(a2, wj[j], acc[2][j]);
        acc[3][j] = fmaf(a3, wj[j], acc[3][j]);
      }
    }
    float scl[8], shf[8];
#pragma unroll
    for (int j=0;j<8;++j) {
      int o = p*64 + 8*h + j;
      float r = g3[o] * rsqrtf(v3[o] + 1e-5f);
      scl[j] = r;
      shf[j] = (b3[o] - m3[o]) * r + bt3[o];
    }
    float vm[8];
#pragma unroll
    for (int j=0;j<8;++j) {
      float q0 = fmaxf(fmaf(acc[0][j], scl[j], shf[j]), 0.f);
      float q1 = fmaxf(fmaf(acc[1][j], scl[j], shf[j]), 0.f);
      float q2 = fmaxf(fmaf(acc[2][j], scl[j], shf[j]), 0.f);
      float q3 = fmaxf(fmaf(acc[3][j], scl[j], shf[j]), 0.f);
      vm[j] = fmaxf(fmaxf(q0,q1), fmaxf(q2,q3));
    }
#pragma unroll
    for (int mk = 8; mk < 64; mk <<= 1) {
#pragma unroll
      for (int j=0;j<8;++j) vm[j] = fmaxf(vm[j], __shfl_xor(vm[j], mk));
    }
    if (g == 0) {
      float* dst = out_feats + (size_t)bid*128 + p*64 + 8*h;
      *(float4*)dst       = make_float4(vm[0],vm[1],vm[2],vm[3]);
      *(float4*)(dst + 4) = make_float4(vm[4],vm[5],vm[6],vm[7]);
    }
  }
}

// ---------------------------------------------------------------------------
extern "C" void kernel_launch(void* const* d_in, const int* in_sizes, int n_in,
                              void* d_out, int out_size, void* d_ws, size_t ws_size,
                              hipStream_t stream) {
  const float* xyzs  = (const float*)d_in[0];
  const float* feats = (const float*)d_in[1];
  const float* w1  = (const float*)d_in[2];
  const float* b1  = (const float*)d_in[3];
  const float* g1  = (const float*)d_in[4];
  const float* bt1 = (const float*)d_in[5];
  const float* m1  = (const float*)d_in[6];
  const float* v1  = (const float*)d_in[7];
  const float* w2  = (const float*)d_in[8];
  const float* b2  = (const float*)d_in[9];
  const float* g2  = (const float*)d_in[10];
  const float* bt2 = (const float*)d_in[11];
  const float* m2  = (const float*)d_in[12];
  const float* v2  = (const float*)d_in[13];
  const float* w3  = (const float*)d_in[14];
  const float* b3  = (const float*)d_in[15];
  const float* g3  = (const float*)d_in[16];
  const float* bt3 = (const float*)d_in[17];
  const float* m3  = (const float*)d_in[18];
  const float* v3  = (const float*)d_in[19];

  float* out       = (float*)d_out;
  float* centers   = out;                          // [8][2048][3]
  float* out_feats = out + (size_t)NB * SCTR * 3;  // [8][2048][128]
  float* wT        = (float*)d_ws;                 // 16576 floats

  // blocks 0..7: FPS; blocks 8..40: weight transpose (33 blocks x 512 thr)
  hipLaunchKernelGGL(fps_transpose_kernel, dim3(NB + 33), dim3(512), 0, stream,
                     xyzs, w1, w2, w3, centers, wT);
  hipLaunchKernelGGL(sa_fused_kernel, dim3(NB * SCTR), dim3(64), 0, stream,
                     xyzs, feats, centers, wT,
                     b1, g1, bt1, m1, v1,
                     b2, g2, bt2, m2, v2,
                     b3, g3, bt3, m3, v3,
                     out_feats);
}

// Round 8
// 2524.649 us; speedup vs baseline: 4.3639x; 1.5941x over previous
//
#include <hip/hip_runtime.h>

// PointNet++ SetAbstraction: FPS -> ball query -> grouped MLP(67->64->64->128, BN+ReLU) -> maxpool
// B=8, N=8192, S=2048, K=32, F=64.
//
// d_out: [8][2048][3] center_xyzs then [8][2048][128] center_feats (fp32).
// d_ws: 16576 floats of transposed weights.
//
// EXACTNESS INVARIANTS (validated R4/R6/R7: absmax 7.8e-3 < 5.4e-2):
//   - discrete-decision math in contract(off) helpers; __f*_rn does NOT block FMA.
//   - np.sum last-axis n=3: FORWARD plain adds (x0+x1)+x2  [FPS dist, |c|^2, |x|^2]
//   - einsum dot: ascending FMA chain fma(c2,x2, fma(c1,x1, c0*x0))  [ball query]
//   - FPS argmax: first-index tie-break. R8 encoding: u64 key
//     (float_bits(bv)<<13)|(8191-idx); bv>=0 so float bits are monotone;
//     pure max(key) == (max bv, tie -> min idx). Total order -> any reduce shape.
//
// PERF LESSONS:
//   R5: dynamically-indexed per-thread arrays get LDS-demoted — named vectors only.
//   R6/R7: __shfl_* lowers to ds_permute (LDS pipe). The old tail burned ~250
//       LDS ops/step (butterfly x8 waves + redundant 16-read scan x8 + coords):
//       ~60% of the 4.3k-cyc step. R8: reduction moved to DPP (VALU pipe):
//       row_shr ladder + bcast15/31 -> lane63; 8 b64 wave-best slots; 3-hop
//       quad_perm/ror4 mini-max after the barrier. ~40 LDS ops/step.
//   sa_fused_kernel byte-identical to R4.

#define NPTS 8192
#define SCTR 2048
#define NB   8
#define KNN  32
#define NF   64

// d = (dx*dx + dy*dy) + dz*dz, exact fp32 mul/add order, NO contraction.
__device__ __forceinline__ float fps_sqdist(float ax, float ay, float az,
                                            float bx, float by, float bz) {
#pragma clang fp contract(off)
  float dx = ax - bx;
  float dy = ay - by;
  float dz = az - bz;
  return (dx * dx + dy * dy) + dz * dz;
}

// (x*x + y*y) + z*z, NO contraction (np.sum forward order, n=3).
__device__ __forceinline__ float sumsq3(float x, float y, float z) {
#pragma clang fp contract(off)
  return (x * x + y * y) + z * z;
}

// Ball-query expanded form: (sc + sx) - 2*dot, NO contraction on the adds.
// dot = ascending-k FMA chain: fma(cz,z, fma(cy,y, cx*x)).
__device__ __forceinline__ float bq_d2(float sc, float sx,
                                       float cx, float cy, float cz,
                                       float x, float y, float z) {
#pragma clang fp contract(off)
  float dt = fmaf(cz, z, fmaf(cy, y, cx * x));
  return (sc + sx) - 2.0f * dt;
}

// u64 max with the partner lane's key fetched via DPP (VALU pipe, no LDS).
// old=src (self): bound-disabled lanes combine with themselves (idempotent max).
template <int CTRL>
__device__ __forceinline__ unsigned long long kmax_dpp(unsigned long long k) {
  int lo = (int)(unsigned int)(k & 0xFFFFFFFFull);
  int hi = (int)(unsigned int)(k >> 32);
  int slo = __builtin_amdgcn_update_dpp(lo, lo, CTRL, 0xF, 0xF, false);
  int shi = __builtin_amdgcn_update_dpp(hi, hi, CTRL, 0xF, 0xF, false);
  unsigned long long sk =
      ((unsigned long long)(unsigned int)shi << 32) | (unsigned int)slo;
  return sk > k ? sk : k;
}

// ---------------------------------------------------------------------------
// Kernel 1: blocks 0..7 = FPS (one block per batch, 512 thr = 8 waves,
// 16 points/thread in NAMED float4 registers); blocks 8..40 = weight transpose.
// Argmax reduction entirely on the VALU pipe via DPP; LDS only for the 8
// wave-best slots, winner-coord broadcast, and final writeback.
// ---------------------------------------------------------------------------
__global__ __launch_bounds__(512, 2) void fps_transpose_kernel(
    const float* __restrict__ xyzs,
    const float* __restrict__ w1, const float* __restrict__ w2, const float* __restrict__ w3,
    float* __restrict__ centers, float* __restrict__ wT)
{
  const int t = threadIdx.x;
  if (blockIdx.x >= NB) {
    int idx = (blockIdx.x - NB) * 512 + t;
    if (idx < 67*64) {
      int c = idx >> 6, o = idx & 63;
      wT[idx] = w1[o*67 + c];
    } else if (idx < 67*64 + 64*64) {
      int r = idx - 67*64; int c = r >> 6, o = r & 63;
      wT[idx] = w2[o*64 + c];
    } else if (idx < 67*64 + 64*64 + 64*128) {
      int r = idx - (67*64 + 64*64); int c = r >> 7, o = r & 127;
      wT[idx] = w3[o*64 + c];
    }
    return;
  }

  const int b = blockIdx.x;
  const float* xb = xyzs + (size_t)b * NPTS * 3;

  __shared__ float sX[NPTS], sY[NPTS], sZ[NPTS];         // 96 KB planar coords
  __shared__ unsigned long long redk[2][8];              // wave-best keys
  __shared__ int hist[SCTR];                             // 8 KB

  // One-time fill of the planar LDS copies (off the hot path).
  for (int i = t; i < NPTS; i += 512) {
    sX[i] = xb[3*i+0];
    sY[i] = xb[3*i+1];
    sZ[i] = xb[3*i+2];
  }
  if (t == 0) hist[0] = 0;   // reference: first center is index 0
  __syncthreads();

  const int t4 = 4 * t;

  // 16 loop-invariant points in NAMED registers (R6/R7-verified pattern).
  const float4 xA = *(const float4*)(sX + 0    + t4);
  const float4 yA = *(const float4*)(sY + 0    + t4);
  const float4 zA = *(const float4*)(sZ + 0    + t4);
  const float4 xB = *(const float4*)(sX + 2048 + t4);
  const float4 yB = *(const float4*)(sY + 2048 + t4);
  const float4 zB = *(const float4*)(sZ + 2048 + t4);
  const float4 xC = *(const float4*)(sX + 4096 + t4);
  const float4 yC = *(const float4*)(sY + 4096 + t4);
  const float4 zC = *(const float4*)(sZ + 4096 + t4);
  const float4 xD = *(const float4*)(sX + 6144 + t4);
  const float4 yD = *(const float4*)(sY + 6144 + t4);
  const float4 zD = *(const float4*)(sZ + 6144 + t4);

  float4 mA = make_float4(1e10f,1e10f,1e10f,1e10f);
  float4 mB = mA, mC = mA, mD = mA;

  float lx = sX[0], ly = sY[0], lz = sZ[0];

#define FPS_PT(MX, MY, MZ, MM, IDX)                                         \
  do {                                                                      \
    float d = fps_sqdist(MX, MY, MZ, lx, ly, lz);                           \
    float m = fminf(MM, d); MM = m;                                         \
    if (m > bv) { bv = m; bg = (IDX); }                                     \
  } while (0)

#define FPS_QUAD(QX, QY, QZ, MV, QOFF)                                      \
  do {                                                                      \
    FPS_PT(QX.x, QY.x, QZ.x, MV.x, (QOFF) + t4 + 0);                        \
    FPS_PT(QX.y, QY.y, QZ.y, MV.y, (QOFF) + t4 + 1);                        \
    FPS_PT(QX.z, QY.z, QZ.z, MV.z, (QOFF) + t4 + 2);                        \
    FPS_PT(QX.w, QY.w, QZ.w, MV.w, (QOFF) + t4 + 3);                        \
  } while (0)

  for (int s = 1; s < SCTR; ++s) {
    float bv = -1.0f; int bg = 0;
    FPS_QUAD(xA, yA, zA, mA, 0);
    FPS_QUAD(xB, yB, zB, mB, 2048);
    FPS_QUAD(xC, yC, zC, mC, 4096);
    FPS_QUAD(xD, yD, zD, mD, 6144);

    // Pack: bv >= 0 after the local loop, so float bits are order-monotone.
    unsigned long long key =
        ((unsigned long long)__float_as_uint(bv) << 13) |
        (unsigned long long)(8191 - bg);

    // Wave-level max on the VALU pipe: row_shr ladder then row broadcasts.
    // After these, lane 63 holds the wave's max key.
    key = kmax_dpp<0x111>(key);   // row_shr:1
    key = kmax_dpp<0x112>(key);   // row_shr:2
    key = kmax_dpp<0x114>(key);   // row_shr:4
    key = kmax_dpp<0x118>(key);   // row_shr:8
    key = kmax_dpp<0x142>(key);   // row_bcast:15
    key = kmax_dpp<0x143>(key);   // row_bcast:31

    int pb = s & 1;   // double-buffered slots: one barrier per step
    if ((t & 63) == 63) redk[pb][t >> 6] = key;
    __syncthreads();

    // Cross-wave: every lane reads slot (lane&7) — 8 unique addrs per wave —
    // then a 3-hop mini-max over the replicated 8-entry groups:
    // quad_perm xor1, quad_perm xor2, row_ror:4 (== xor4 under 8-replication).
    unsigned long long k8 = redk[pb][t & 7];
    k8 = kmax_dpp<0xB1>(k8);      // quad_perm [1,0,3,2]
    k8 = kmax_dpp<0x4E>(k8);      // quad_perm [2,3,0,1]
    k8 = kmax_dpp<0x124>(k8);     // row_ror:4

    int i0 = 8191 - (int)(k8 & 0x1FFFull);
    // Winner coords: broadcast LDS reads (same address all lanes — free).
    lx = sX[i0]; ly = sY[i0]; lz = sZ[i0];
    if (t == 0) hist[s] = i0;
  }
#undef FPS_QUAD
#undef FPS_PT
  __syncthreads();

  for (int s = t; s < SCTR; s += 512) {
    int i = hist[s];
    float* o = centers + ((size_t)b * SCTR + s) * 3;
    o[0] = sX[i]; o[1] = sY[i]; o[2] = sZ[i];
  }
}

// ---------------------------------------------------------------------------
// Kernel 2: one 64-thread wave per center. Ball query (first K ascending
// index within radius, exact expanded-form d2), gather to LDS, 3-layer MLP
// with per-lane 4k x 8o register tile, BN+ReLU, maxpool over K, store.
// (byte-identical to the R4 passing version)
// ---------------------------------------------------------------------------
__global__ __launch_bounds__(64) void sa_fused_kernel(
    const float* __restrict__ xyzs, const float* __restrict__ feats,
    const float* centers, const float* __restrict__ wT,
    const float* __restrict__ b1, const float* __restrict__ g1, const float* __restrict__ bt1,
    const float* __restrict__ m1, const float* __restrict__ v1,
    const float* __restrict__ b2, const float* __restrict__ g2, const float* __restrict__ bt2,
    const float* __restrict__ m2, const float* __restrict__ v2,
    const float* __restrict__ b3, const float* __restrict__ g3, const float* __restrict__ bt3,
    const float* __restrict__ m3, const float* __restrict__ v3,
    float* out_feats)
{
  constexpr float R2 = (float)(0.2 * 0.2);  // f32(0.04000000000000001) — matches ref predicate
  const int bid  = blockIdx.x;
  const int b    = bid >> 11;
  const int lane = threadIdx.x;
  const float* xb = xyzs + (size_t)b * NPTS * 3;
  const float* cp = centers + (size_t)bid * 3;
  float cx = cp[0], cy = cp[1], cz = cp[2];
  float sc = sumsq3(cx, cy, cz);

  __shared__ int   gidx[KNN];
  __shared__ float in_[32*67];   // stride 67 (conflict-free for the 4k in-reads)
  __shared__ float y_[32*65];    // stride 65

  // ---- ball query: first 32 in-radius points by ascending index ----
  int cnt = 0;
  for (int base = 0; base < NPTS && cnt < KNN; base += 64) {
    int n = base + lane;
    float x = xb[n*3+0], y = xb[n*3+1], z = xb[n*3+2];
    float sx = sumsq3(x, y, z);
    float d2 = bq_d2(sc, sx, cx, cy, cz, x, y, z);
    bool within = (d2 <= R2);
    unsigned long long mk = __ballot(within);
    int rank = __popcll(mk & ((1ull << lane) - 1ull));
    int slot = cnt + rank;
    if (within && slot < KNN) gidx[slot] = n;
    cnt += (int)__popcll(mk);
  }
  if (cnt > KNN) cnt = KNN;
  __syncthreads();

  // ---- gather: in_[k][0..2] = xyz - center, in_[k][3..66] = feats; zeros if invalid ----
#pragma unroll 4
  for (int k = 0; k < KNN; ++k) {
    int gk = (k < cnt) ? gidx[k] : -1;
    float fv = 0.f, xv = 0.f;
    if (gk >= 0) {
      fv = feats[((size_t)b * NPTS + gk) * NF + lane];
      if (lane < 3) xv = xb[gk*3 + lane] - cp[lane];  // exact single op
    }
    in_[k*67 + 3 + lane] = fv;
    if (lane < 3) in_[k*67 + lane] = xv;
  }
  __syncthreads();

  const int g = lane >> 3;  // k-group: k = 4g..4g+3
  const int h = lane & 7;   // o-group: o = 8h..8h+7
  const float* w1T = wT;                  // [67][64]
  const float* w2T = wT + 67*64;          // [64][64]
  const float* w3T = wT + 67*64 + 64*64;  // [64][128]

  // ---- Layer 1: 67 -> 64 ----
  {
    float acc[4][8];
#pragma unroll
    for (int i=0;i<4;++i)
#pragma unroll
      for (int j=0;j<8;++j) acc[i][j]=0.f;
    for (int c = 0; c < 67; ++c) {
      float a0 = in_[(4*g+0)*67 + c];
      float a1 = in_[(4*g+1)*67 + c];
      float a2 = in_[(4*g+2)*67 + c];
      float a3 = in_[(4*g+3)*67 + c];
      const float* wr = w1T + c*64 + 8*h;
      float4 wv0 = *(const float4*)(wr);
      float4 wv1 = *(const float4*)(wr + 4);
      float wj[8] = {wv0.x,wv0.y,wv0.z,wv0.w,wv1.x,wv1.y,wv1.z,wv1.w};
#pragma unroll
      for (int j=0;j<8;++j) {
        acc[0][j] = fmaf(a0, wj[j], acc[0][j]);
        acc[1][j] = fmaf(a1, wj[j], acc[1][j]);
        acc[2][j] = fmaf(a2, wj[j], acc[2][j]);
        acc[3][j] = fmaf(a3, wj[j], acc[3][j]);
      }
    }
    float scl[8], shf[8];
#pragma unroll
    for (int j=0;j<8;++j) {
      int o = 8*h + j;
      float r = g1[o] * rsqrtf(v1[o] + 1e-5f);
      scl[j] = r;
      shf[j] = (b1[o] - m1[o]) * r + bt1[o];
    }
#pragma unroll
    for (int i=0;i<4;++i) {
      int k = 4*g + i;
#pragma unroll
      for (int j=0;j<8;++j)
        y_[k*65 + 8*h + j] = fmaxf(fmaf(acc[i][j], scl[j], shf[j]), 0.f);
    }
  }
  __syncthreads();

  // ---- Layer 2: 64 -> 64 (reads y_, writes in_ reused at stride 65) ----
  {
    float acc[4][8];
#pragma unroll
    for (int i=0;i<4;++i)
#pragma unroll
      for (int j=0;j<8;++j) acc[i][j]=0.f;
    for (int c = 0; c < 64; ++c) {
      float a0 = y_[(4*g+0)*65 + c];
      float a1 = y_[(4*g+1)*65 + c];
      float a2 = y_[(4*g+2)*65 + c];
      float a3 = y_[(4*g+3)*65 + c];
      const float* wr = w2T + c*64 + 8*h;
      float4 wv0 = *(const float4*)(wr);
      float4 wv1 = *(const float4*)(wr + 4);
      float wj[8] = {wv0.x,wv0.y,wv0.z,wv0.w,wv1.x,wv1.y,wv1.z,wv1.w};
#pragma unroll
      for (int j=0;j<8;++j) {
        acc[0][j] = fmaf(a0, wj[j], acc[0][j]);
        acc[1][j] = fmaf(a1, wj[j], acc[1][j]);
        acc[2][j] = fmaf(a2, wj[j], acc[2][j]);
        acc[3][j] = fmaf(a3, wj[j], acc[3][j]);
      }
    }
    float scl[8], shf[8];
#pragma unroll
    for (int j=0;j<8;++j) {
      int o = 8*h + j;
      float r = g2[o] * rsqrtf(v2[o] + 1e-5f);
      scl[j] = r;
      shf[j] = (b2[o] - m2[o]) * r + bt2[o];
    }
    __syncthreads();  // order old in_ reads before overwrite
#pragma unroll
    for (int i=0;i<4;++i) {
      int k = 4*g + i;
#pragma unroll
      for (int j=0;j<8;++j)
        in_[k*65 + 8*h + j] = fmaxf(fmaf(acc[i][j], scl[j], shf[j]), 0.f);
    }
  }
  __syncthreads();

  // ---- Layer 3: 64 -> 128 in two o-passes, BN+ReLU, maxpool over k, store ----
  for (int p = 0; p < 2; ++p) {
    float acc[4][8];
#pragma unroll
    for (int i=0;i<4;++i)
#pragma unroll
      for (int j=0;j<8;++j) acc[i][j]=0.f;
    for (int c = 0; c < 64; ++c) {
      float a0 = in_[(4*g+0)*65 + c];
      float a1 = in_[(4*g+1)*65 + c];
      float a2 = in_[(4*g+2)*65 + c];
      float a3 = in_[(4*g+3)*65 + c];
      const float* wr = w3T + c*128 + p*64 + 8*h;
      float4 wv0 = *(const float4*)(wr);
      float4 wv1 = *(const float4*)(wr + 4);
      float wj[8] = {wv0.x,wv0.y,wv0.z,wv0.w,wv1.x,wv1.y,wv1.z,wv1.w};
#pragma unroll
      for (int j=0;j<8;++j) {
        acc[0][j] = fmaf(a0, wj[j], acc[0][j]);
        acc[1][j] = fmaf(a1, wj[j], acc[1][j]);
        acc[2][j] = fmaf(a2, wj[j], acc[2][j]);
        acc[3][j] = fmaf(a3, wj[j], acc[3][j]);
      }
    }
    float scl[8], shf[8];
#pragma unroll
    for (int j=0;j<8;++j) {
      int o = p*64 + 8*h + j;
      float r = g3[o] * rsqrtf(v3[o] + 1e-5f);
      scl[j] = r;
      shf[j] = (b3[o] - m3[o]) * r + bt3[o];
    }
    float vm[8];
#pragma unroll
    for (int j=0;j<8;++j) {
      float q0 = fmaxf(fmaf(acc[0][j], scl[j], shf[j]), 0.f);
      float q1 = fmaxf(fmaf(acc[1][j], scl[j], shf[j]), 0.f);
      float q2 = fmaxf(fmaf(acc[2][j], scl[j], shf[j]), 0.f);
      float q3 = fmaxf(fmaf(acc[3][j], scl[j], shf[j]), 0.f);
      vm[j] = fmaxf(fmaxf(q0,q1), fmaxf(q2,q3));
    }
#pragma unroll
    for (int mk = 8; mk < 64; mk <<= 1) {
#pragma unroll
      for (int j=0;j<8;++j) vm[j] = fmaxf(vm[j], __shfl_xor(vm[j], mk));
    }
    if (g == 0) {
      float* dst = out_feats + (size_t)bid*128 + p*64 + 8*h;
      *(float4*)dst       = make_float4(vm[0],vm[1],vm[2],vm[3]);
      *(float4*)(dst + 4) = make_float4(vm[4],vm[5],vm[6],vm[7]);
    }
  }
}

// ---------------------------------------------------------------------------
extern "C" void kernel_launch(void* const* d_in, const int* in_sizes, int n_in,
                              void* d_out, int out_size, void* d_ws, size_t ws_size,
                              hipStream_t stream) {
  const float* xyzs  = (const float*)d_in[0];
  const float* feats = (const float*)d_in[1];
  const float* w1  = (const float*)d_in[2];
  const float* b1  = (const float*)d_in[3];
  const float* g1  = (const float*)d_in[4];
  const float* bt1 = (const float*)d_in[5];
  const float* m1  = (const float*)d_in[6];
  const float* v1  = (const float*)d_in[7];
  const float* w2  = (const float*)d_in[8];
  const float* b2  = (const float*)d_in[9];
  const float* g2  = (const float*)d_in[10];
  const float* bt2 = (const float*)d_in[11];
  const float* m2  = (const float*)d_in[12];
  const float* v2  = (const float*)d_in[13];
  const float* w3  = (const float*)d_in[14];
  const float* b3  = (const float*)d_in[15];
  const float* g3  = (const float*)d_in[16];
  const float* bt3 = (const float*)d_in[17];
  const float* m3  = (const float*)d_in[18];
  const float* v3  = (const float*)d_in[19];

  float* out       = (float*)d_out;
  float* centers   = out;                          // [8][2048][3]
  float* out_feats = out + (size_t)NB * SCTR * 3;  // [8][2048][128]
  float* wT        = (float*)d_ws;                 // 16576 floats

  // blocks 0..7: FPS; blocks 8..40: weight transpose (33 blocks x 512 thr)
  hipLaunchKernelGGL(fps_transpose_kernel, dim3(NB + 33), dim3(512), 0, stream,
                     xyzs, w1, w2, w3, centers, wT);
  hipLaunchKernelGGL(sa_fused_kernel, dim3(NB * SCTR), dim3(64), 0, stream,
                     xyzs, feats, centers, wT,
                     b1, g1, bt1, m1, v1,
                     b2, g2, bt2, m2, v2,
                     b3, g3, bt3, m3, v3,
                     out_feats);
}